// Round 5
// baseline (190.220 us; speedup 1.0000x reference)
//
#include <hip/hip_runtime.h>
#include <hip/hip_fp16.h>

#define N_NODES 100000
#define N_EDGES 400000
#define SCAN_BLOCKS ((N_NODES + 255) / 256)   // 391

// ---------- build CSR by dst: histogram ----------
__global__ __launch_bounds__(256) void hist_kernel(const int* __restrict__ ei,
                                                   int* __restrict__ deg) {
    int e = blockIdx.x * 256 + threadIdx.x;
    if (e < N_EDGES) atomicAdd(&deg[ei[N_EDGES + e]], 1);
}

// block-local exclusive scan of deg -> rowptr(local), block sums -> psum
__global__ __launch_bounds__(256) void scanA_kernel(const int* __restrict__ deg,
                                                    int* __restrict__ rowptr,
                                                    int* __restrict__ psum) {
    __shared__ int sm[256];
    int i = blockIdx.x * 256 + threadIdx.x;
    int v = (i < N_NODES) ? deg[i] : 0;
    sm[threadIdx.x] = v;
    __syncthreads();
    #pragma unroll
    for (int off = 1; off < 256; off <<= 1) {
        int t = (threadIdx.x >= off) ? sm[threadIdx.x - off] : 0;
        __syncthreads();
        sm[threadIdx.x] += t;
        __syncthreads();
    }
    if (i < N_NODES) rowptr[i] = sm[threadIdx.x] - v;
    if (threadIdx.x == 255) psum[blockIdx.x] = sm[255];
}

// merged scanB+scanC
__global__ __launch_bounds__(256) void scanBC_kernel(const int* __restrict__ psum,
                                                     int* __restrict__ rowptr,
                                                     int* __restrict__ cursor) {
    __shared__ int sm[8];
    int bid = blockIdx.x, tid = threadIdx.x;
    int acc = 0;
    for (int t = tid; t < bid; t += 256) acc += psum[t];
    #pragma unroll
    for (int off = 32; off; off >>= 1) acc += __shfl_down(acc, off, 64);
    if ((tid & 63) == 0) sm[tid >> 6] = acc;
    __syncthreads();
    int base = sm[0] + sm[1] + sm[2] + sm[3];
    int i = bid * 256 + tid;
    if (i < N_NODES) {
        int r = rowptr[i] + base;
        rowptr[i] = r;
        cursor[i] = r;
    }
    if (i == 0) rowptr[N_NODES] = N_EDGES;
}

// scatter edge payload into dst-sorted slots: A={ea0,ea1,ea2,src}, B={x[s],0}
__global__ __launch_bounds__(256) void scatter_kernel(const int* __restrict__ ei,
                                                      const float* __restrict__ ea,
                                                      const float* __restrict__ x,
                                                      int* __restrict__ cursor,
                                                      float4* __restrict__ edataA,
                                                      float4* __restrict__ edataB) {
    int e = blockIdx.x * 256 + threadIdx.x;
    if (e >= N_EDGES) return;
    int s = ei[e], d = ei[N_EDGES + e];
    int pos = atomicAdd(&cursor[d], 1);
    edataA[pos] = make_float4(ea[e*3], ea[e*3+1], ea[e*3+2], __int_as_float(s));
    edataB[pos] = make_float4(x[s*3], x[s*3+1], x[s*3+2], 0.f);
}

// ---------- conv1: one WAVE per node (lanes = (j2,o)), no divergence ----------
__global__ __launch_bounds__(256) void conv1_kernel(const int* __restrict__ rowptr,
                                                    const float4* __restrict__ edataA,
                                                    const float4* __restrict__ edataB,
                                                    const float* __restrict__ x,
                                                    const float* __restrict__ Wn1,
                                                    const float* __restrict__ bn1,
                                                    const float* __restrict__ root1,
                                                    const float* __restrict__ b1,
                                                    float* __restrict__ h1) {
    int n = (blockIdx.x * 256 + threadIdx.x) >> 6;
    int lane = threadIdx.x & 63;
    int j2 = lane >> 5, o = lane & 31;
    if (n >= N_NODES) return;
    float W[3][3], bb[3];
    #pragma unroll
    for (int d2 = 0; d2 < 3; ++d2)
        #pragma unroll
        for (int d = 0; d < 3; ++d) W[d2][d] = Wn1[d2*96 + d*32 + o];
    #pragma unroll
    for (int d = 0; d < 3; ++d) bb[d] = bn1[d*32 + o];

    int j0 = rowptr[n], j1 = rowptr[n + 1];
    float acc = 0.f;
    for (int j = j0 + j2; j < j1; j += 2) {
        float4 eA = edataA[j], eB = edataB[j];
        float wd0 = fmaf(eA.x, W[0][0], fmaf(eA.y, W[1][0], fmaf(eA.z, W[2][0], bb[0])));
        float wd1 = fmaf(eA.x, W[0][1], fmaf(eA.y, W[1][1], fmaf(eA.z, W[2][1], bb[1])));
        float wd2 = fmaf(eA.x, W[0][2], fmaf(eA.y, W[1][2], fmaf(eA.z, W[2][2], bb[2])));
        acc += fmaf(eB.x, wd0, fmaf(eB.y, wd1, eB.z * wd2));
    }
    acc += __shfl_xor(acc, 32);          // fold the two halves
    if (j2 == 0) {
        float v = acc + b1[o];
        v = fmaf(x[n*3],   root1[o],      v);
        v = fmaf(x[n*3+1], root1[32 + o], v);
        v = fmaf(x[n*3+2], root1[64 + o], v);
        h1[(size_t)n*32 + o] = fmaxf(v, 0.f);
    }
}

// ---------- prep2: G2[n][o] = {hW0, hW1, hW2, hB} packed as 2x half2 (8 B) ----------
__global__ __launch_bounds__(256) void prep2_kernel(const float* __restrict__ h1,
                                                    const float* __restrict__ Wn2,
                                                    const float* __restrict__ bn2,
                                                    uint2* __restrict__ G2h) {
    int o = threadIdx.x & 31;
    float w0[32], w1[32], w2[32], w3[32];
    #pragma unroll
    for (int i = 0; i < 32; ++i) {
        w0[i] = Wn2[         i*32 + o];
        w1[i] = Wn2[1024 +   i*32 + o];
        w2[i] = Wn2[2048 +   i*32 + o];
        w3[i] = bn2[         i*32 + o];
    }
    int g = (blockIdx.x * 256 + threadIdx.x) >> 5;
    int gstep = (gridDim.x * 256) >> 5;
    for (int n = g; n < N_NODES; n += gstep) {
        const float* __restrict__ hr = h1 + (size_t)n * 32;
        float g0 = 0.f, g1 = 0.f, g2 = 0.f, g3 = 0.f;
        #pragma unroll
        for (int i = 0; i < 32; ++i) {
            float hi = hr[i];
            g0 = fmaf(hi, w0[i], g0);
            g1 = fmaf(hi, w1[i], g1);
            g2 = fmaf(hi, w2[i], g2);
            g3 = fmaf(hi, w3[i], g3);
        }
        __half2 ab = __floats2half2_rn(g0, g1);
        __half2 cd = __floats2half2_rn(g2, g3);
        uint2 p;
        p.x = *(const unsigned int*)&ab;
        p.y = *(const unsigned int*)&cd;
        G2h[(size_t)n*32 + o] = p;
    }
}

// ---------- conv2 gather: wave-per-node, fp16 G2 (4 lines/edge), + root2 ----------
__global__ __launch_bounds__(256) void conv2_kernel(const int* __restrict__ rowptr,
                                                    const float4* __restrict__ edataA,
                                                    const uint2* __restrict__ G2h,
                                                    const float* __restrict__ h1,
                                                    const float* __restrict__ root2,
                                                    const float* __restrict__ b2,
                                                    float* __restrict__ h2out) {
    int n = (blockIdx.x * 256 + threadIdx.x) >> 6;
    int lane = threadIdx.x & 63;
    int j2 = lane >> 5, o = lane & 31;
    if (n >= N_NODES) return;
    int j0 = rowptr[n], j1 = rowptr[n + 1];
    float acc = 0.f;
    for (int j = j0 + j2; j < j1; j += 2) {
        float4 e = edataA[j];
        uint2 p = G2h[(size_t)__float_as_int(e.w)*32 + o];
        __half2 ab = *(const __half2*)&p.x;
        __half2 cd = *(const __half2*)&p.y;
        float2 f01 = __half22float2(ab);
        float2 f23 = __half22float2(cd);
        acc += fmaf(e.x, f01.x, fmaf(e.y, f01.y, fmaf(e.z, f23.x, f23.y)));
    }
    acc += __shfl_xor(acc, 32);          // fold halves
    if (j2 == 0) {
        float v = acc + b2[o];
        const float* __restrict__ hr = h1 + (size_t)n * 32;
        #pragma unroll
        for (int i = 0; i < 32; ++i) v = fmaf(hr[i], root2[i*32 + o], v);
        h2out[(size_t)n*32 + o] = fmaxf(v, 0.f);
    }
}

// ---------- FC1 + FC2: node-per-thread, wave-uniform weights ----------
__global__ __launch_bounds__(256) void fc_kernel(const float* __restrict__ h2,
                                                 const float* __restrict__ Wf1,
                                                 const float* __restrict__ bf1,
                                                 const float* __restrict__ Wf2,
                                                 const float* __restrict__ bf2,
                                                 float* __restrict__ out) {
    int n = blockIdx.x * 256 + threadIdx.x;
    if (n >= N_NODES) return;
    float hr[32];
    const float4* hv = (const float4*)(h2 + (size_t)n * 32);
    #pragma unroll
    for (int j4 = 0; j4 < 8; ++j4) {
        float4 t = hv[j4];
        hr[j4*4+0] = t.x; hr[j4*4+1] = t.y; hr[j4*4+2] = t.z; hr[j4*4+3] = t.w;
    }
    float acc2 = bf2[0];
    #pragma unroll
    for (int j = 0; j < 32; ++j) {
        float a = bf1[j];
        #pragma unroll
        for (int i = 0; i < 32; ++i) a = fmaf(hr[i], Wf1[i*32 + j], a);
        acc2 = fmaf(fmaxf(a, 0.f), Wf2[j], acc2);
    }
    out[n] = acc2;
}

extern "C" void kernel_launch(void* const* d_in, const int* in_sizes, int n_in,
                              void* d_out, int out_size, void* d_ws, size_t ws_size,
                              hipStream_t stream) {
    const float* x     = (const float*)d_in[0];
    const int*   ei    = (const int*)  d_in[1];
    const float* ea    = (const float*)d_in[2];
    const float* Wn1   = (const float*)d_in[3];
    const float* bn1   = (const float*)d_in[4];
    const float* root1 = (const float*)d_in[5];
    const float* b1    = (const float*)d_in[6];
    const float* Wn2   = (const float*)d_in[7];
    const float* bn2   = (const float*)d_in[8];
    const float* root2 = (const float*)d_in[9];
    const float* b2    = (const float*)d_in[10];
    const float* Wf1   = (const float*)d_in[11];
    const float* bf1   = (const float*)d_in[12];
    const float* Wf2   = (const float*)d_in[13];
    const float* bf2   = (const float*)d_in[14];
    float* out = (float*)d_out;

    // workspace carve (~65 MB)
    float*  h1     = (float*)d_ws;                        // [N,32] f32
    float*  h2     = h1 + (size_t)N_NODES*32;             // [N,32] f32
    uint2*  G2h    = (uint2*)(h2 + (size_t)N_NODES*32);   // [N,32] fp16x4
    float4* edataA = (float4*)(G2h + (size_t)N_NODES*32); // [E]
    float4* edataB = edataA + N_EDGES;                    // [E]
    int*    deg    = (int*)(edataB + N_EDGES);            // [N]
    int*    rowptr = deg + N_NODES;                       // [N+1]
    int*    cursor = rowptr + N_NODES + 1;                // [N]
    int*    psum   = cursor + N_NODES;                    // [SCAN_BLOCKS]

    hipMemsetAsync(deg, 0, N_NODES * sizeof(int), stream);

    int eb   = (N_EDGES + 255) / 256;                     // 1563
    int nb   = (N_NODES + 255) / 256;                     // 391
    int nb64 = (N_NODES * 64 + 255) / 256;                // 25000

    hist_kernel   <<<eb, 256, 0, stream>>>(ei, deg);
    scanA_kernel  <<<SCAN_BLOCKS, 256, 0, stream>>>(deg, rowptr, psum);
    scanBC_kernel <<<SCAN_BLOCKS, 256, 0, stream>>>(psum, rowptr, cursor);
    scatter_kernel<<<eb, 256, 0, stream>>>(ei, ea, x, cursor, edataA, edataB);
    conv1_kernel  <<<nb64, 256, 0, stream>>>(rowptr, edataA, edataB, x, Wn1, bn1, root1, b1, h1);
    prep2_kernel  <<<1536, 256, 0, stream>>>(h1, Wn2, bn2, G2h);
    conv2_kernel  <<<nb64, 256, 0, stream>>>(rowptr, edataA, G2h, h1, root2, b2, h2);
    fc_kernel     <<<nb, 256, 0, stream>>>(h2, Wf1, bf1, Wf2, bf2, out);
}

// Round 6
// 176.119 us; speedup vs baseline: 1.0801x; 1.0801x over previous
//
#include <hip/hip_runtime.h>

#define N_NODES 100000
#define N_EDGES 400000
#define N_HALF  50000
#define SCAN_BLOCKS ((N_NODES + 255) / 256)   // 391

// ---------- build CSR by dst: histogram ----------
__global__ __launch_bounds__(256) void hist_kernel(const int* __restrict__ ei,
                                                   int* __restrict__ deg) {
    int e = blockIdx.x * 256 + threadIdx.x;
    if (e < N_EDGES) atomicAdd(&deg[ei[N_EDGES + e]], 1);
}

// block-local exclusive scan of deg -> rowptr(local), block sums -> psum
__global__ __launch_bounds__(256) void scanA_kernel(const int* __restrict__ deg,
                                                    int* __restrict__ rowptr,
                                                    int* __restrict__ psum) {
    __shared__ int sm[256];
    int i = blockIdx.x * 256 + threadIdx.x;
    int v = (i < N_NODES) ? deg[i] : 0;
    sm[threadIdx.x] = v;
    __syncthreads();
    #pragma unroll
    for (int off = 1; off < 256; off <<= 1) {
        int t = (threadIdx.x >= off) ? sm[threadIdx.x - off] : 0;
        __syncthreads();
        sm[threadIdx.x] += t;
        __syncthreads();
    }
    if (i < N_NODES) rowptr[i] = sm[threadIdx.x] - v;
    if (threadIdx.x == 255) psum[blockIdx.x] = sm[255];
}

// merged scanB+scanC
__global__ __launch_bounds__(256) void scanBC_kernel(const int* __restrict__ psum,
                                                     int* __restrict__ rowptr,
                                                     int* __restrict__ cursor) {
    __shared__ int sm[8];
    int bid = blockIdx.x, tid = threadIdx.x;
    int acc = 0;
    for (int t = tid; t < bid; t += 256) acc += psum[t];
    #pragma unroll
    for (int off = 32; off; off >>= 1) acc += __shfl_down(acc, off, 64);
    if ((tid & 63) == 0) sm[tid >> 6] = acc;
    __syncthreads();
    int base = sm[0] + sm[1] + sm[2] + sm[3];
    int i = bid * 256 + tid;
    if (i < N_NODES) {
        int r = rowptr[i] + base;
        rowptr[i] = r;
        cursor[i] = r;
    }
    if (i == 0) rowptr[N_NODES] = N_EDGES;
}

// scatter edge payload into dst-sorted slots: A={ea0,ea1,ea2,src}, B={x[s],0}
__global__ __launch_bounds__(256) void scatter_kernel(const int* __restrict__ ei,
                                                      const float* __restrict__ ea,
                                                      const float* __restrict__ x,
                                                      int* __restrict__ cursor,
                                                      float4* __restrict__ edataA,
                                                      float4* __restrict__ edataB) {
    int e = blockIdx.x * 256 + threadIdx.x;
    if (e >= N_EDGES) return;
    int s = ei[e], d = ei[N_EDGES + e];
    int pos = atomicAdd(&cursor[d], 1);
    edataA[pos] = make_float4(ea[e*3], ea[e*3+1], ea[e*3+2], __int_as_float(s));
    edataB[pos] = make_float4(x[s*3], x[s*3+1], x[s*3+2], 0.f);
}

// ---------- conv1 aggregation + node update (R4 version) ----------
__global__ __launch_bounds__(256) void conv1_kernel(const int* __restrict__ rowptr,
                                                    const float4* __restrict__ edataA,
                                                    const float4* __restrict__ edataB,
                                                    const float* __restrict__ x,
                                                    const float* __restrict__ Wn1,
                                                    const float* __restrict__ bn1,
                                                    const float* __restrict__ root1,
                                                    const float* __restrict__ b1,
                                                    float* __restrict__ h1) {
    int gid = blockIdx.x * 256 + threadIdx.x;
    int n = gid >> 5, o = gid & 31;
    if (n >= N_NODES) return;
    float W[3][3], bb[3];
    #pragma unroll
    for (int d2 = 0; d2 < 3; ++d2)
        #pragma unroll
        for (int d = 0; d < 3; ++d) W[d2][d] = Wn1[d2*96 + d*32 + o];
    #pragma unroll
    for (int d = 0; d < 3; ++d) bb[d] = bn1[d*32 + o];

    int j0 = rowptr[n], j1 = rowptr[n + 1];
    float acc0 = 0.f, acc1 = 0.f;
    int j = j0;
    for (; j + 2 <= j1; j += 2) {
        float4 eA0 = edataA[j],   eB0 = edataB[j];
        float4 eA1 = edataA[j+1], eB1 = edataB[j+1];
        float wd0 = fmaf(eA0.x, W[0][0], fmaf(eA0.y, W[1][0], fmaf(eA0.z, W[2][0], bb[0])));
        float wd1 = fmaf(eA0.x, W[0][1], fmaf(eA0.y, W[1][1], fmaf(eA0.z, W[2][1], bb[1])));
        float wd2 = fmaf(eA0.x, W[0][2], fmaf(eA0.y, W[1][2], fmaf(eA0.z, W[2][2], bb[2])));
        acc0 += fmaf(eB0.x, wd0, fmaf(eB0.y, wd1, eB0.z * wd2));
        float ud0 = fmaf(eA1.x, W[0][0], fmaf(eA1.y, W[1][0], fmaf(eA1.z, W[2][0], bb[0])));
        float ud1 = fmaf(eA1.x, W[0][1], fmaf(eA1.y, W[1][1], fmaf(eA1.z, W[2][1], bb[1])));
        float ud2 = fmaf(eA1.x, W[0][2], fmaf(eA1.y, W[1][2], fmaf(eA1.z, W[2][2], bb[2])));
        acc1 += fmaf(eB1.x, ud0, fmaf(eB1.y, ud1, eB1.z * ud2));
    }
    if (j < j1) {
        float4 eA0 = edataA[j], eB0 = edataB[j];
        float wd0 = fmaf(eA0.x, W[0][0], fmaf(eA0.y, W[1][0], fmaf(eA0.z, W[2][0], bb[0])));
        float wd1 = fmaf(eA0.x, W[0][1], fmaf(eA0.y, W[1][1], fmaf(eA0.z, W[2][1], bb[1])));
        float wd2 = fmaf(eA0.x, W[0][2], fmaf(eA0.y, W[1][2], fmaf(eA0.z, W[2][2], bb[2])));
        acc0 += fmaf(eB0.x, wd0, fmaf(eB0.y, wd1, eB0.z * wd2));
    }
    float v = acc0 + acc1 + b1[o];
    v = fmaf(x[n*3],   root1[o],      v);
    v = fmaf(x[n*3+1], root1[32 + o], v);
    v = fmaf(x[n*3+2], root1[64 + o], v);
    h1[(size_t)n*32 + o] = fmaxf(v, 0.f);
}

// ---------- per-node precompute G2[n] = [hW0 | hW1 | hW2 | hB] (f32, R4) ----------
__global__ __launch_bounds__(256) void prep2_kernel(const float* __restrict__ h1,
                                                    const float* __restrict__ Wn2,
                                                    const float* __restrict__ bn2,
                                                    float4* __restrict__ G2) {
    int o = threadIdx.x & 31;
    float w0[32], w1[32], w2[32], w3[32];
    #pragma unroll
    for (int i = 0; i < 32; ++i) {
        w0[i] = Wn2[         i*32 + o];
        w1[i] = Wn2[1024 +   i*32 + o];
        w2[i] = Wn2[2048 +   i*32 + o];
        w3[i] = bn2[         i*32 + o];
    }
    int g = (blockIdx.x * 256 + threadIdx.x) >> 5;
    int gstep = (gridDim.x * 256) >> 5;
    for (int n = g; n < N_NODES; n += gstep) {
        const float* __restrict__ hr = h1 + (size_t)n * 32;
        float g0 = 0.f, g1 = 0.f, g2 = 0.f, g3 = 0.f;
        #pragma unroll
        for (int i = 0; i < 32; ++i) {
            float hi = hr[i];
            g0 = fmaf(hi, w0[i], g0);
            g1 = fmaf(hi, w1[i], g1);
            g2 = fmaf(hi, w2[i], g2);
            g3 = fmaf(hi, w3[i], g3);
        }
        G2[(size_t)n*32 + o] = make_float4(g0, g1, g2, g3);
    }
}

// ---------- conv2: TWO nodes per 32-lane group (MLP test) + root2 + FC1 + FC2 ----------
__device__ __forceinline__ void conv2_epilogue(int n, int o, float acc,
                                               const float* __restrict__ h1,
                                               const float* __restrict__ root2,
                                               const float* __restrict__ b2,
                                               const float* __restrict__ Wf1,
                                               const float* __restrict__ bf1,
                                               const float* __restrict__ Wf2,
                                               const float* __restrict__ bf2,
                                               float* __restrict__ out) {
    const float* __restrict__ hr = h1 + (size_t)n * 32;
    float v = acc + b2[o];
    #pragma unroll
    for (int i = 0; i < 32; ++i) v = fmaf(hr[i], root2[i*32 + o], v);
    float h2 = fmaxf(v, 0.f);
    float a3 = bf1[o];
    #pragma unroll
    for (int i = 0; i < 32; ++i) a3 = fmaf(__shfl(h2, i, 32), Wf1[i*32 + o], a3);
    float h3 = fmaxf(a3, 0.f);
    float p = h3 * Wf2[o];
    #pragma unroll
    for (int off = 16; off; off >>= 1) p += __shfl_down(p, off, 32);
    if (o == 0) out[n] = p + bf2[0];
}

__global__ __launch_bounds__(256) void conv2_kernel(const int* __restrict__ rowptr,
                                                    const float4* __restrict__ edataA,
                                                    const float4* __restrict__ G2,
                                                    const float* __restrict__ h1,
                                                    const float* __restrict__ root2,
                                                    const float* __restrict__ b2,
                                                    const float* __restrict__ Wf1,
                                                    const float* __restrict__ bf1,
                                                    const float* __restrict__ Wf2,
                                                    const float* __restrict__ bf2,
                                                    float* __restrict__ out) {
    int gid = blockIdx.x * 256 + threadIdx.x;
    int t = gid >> 5, o = gid & 31;
    if (t >= N_HALF) return;
    int nA = t, nB = t + N_HALF;

    int jA = rowptr[nA], jA1 = rowptr[nA + 1];
    int jB = rowptr[nB], jB1 = rowptr[nB + 1];
    float aA0 = 0.f, aA1 = 0.f, aB0 = 0.f, aB1 = 0.f;

    // combined loop: 4 independent gather chains in flight
    while (jA + 2 <= jA1 && jB + 2 <= jB1) {
        float4 eA0 = edataA[jA], eA1 = edataA[jA+1];
        float4 eB0 = edataA[jB], eB1 = edataA[jB+1];
        float4 gA0 = G2[(size_t)__float_as_int(eA0.w)*32 + o];
        float4 gA1 = G2[(size_t)__float_as_int(eA1.w)*32 + o];
        float4 gB0 = G2[(size_t)__float_as_int(eB0.w)*32 + o];
        float4 gB1 = G2[(size_t)__float_as_int(eB1.w)*32 + o];
        aA0 += fmaf(eA0.x, gA0.x, fmaf(eA0.y, gA0.y, fmaf(eA0.z, gA0.z, gA0.w)));
        aA1 += fmaf(eA1.x, gA1.x, fmaf(eA1.y, gA1.y, fmaf(eA1.z, gA1.z, gA1.w)));
        aB0 += fmaf(eB0.x, gB0.x, fmaf(eB0.y, gB0.y, fmaf(eB0.z, gB0.z, gB0.w)));
        aB1 += fmaf(eB1.x, gB1.x, fmaf(eB1.y, gB1.y, fmaf(eB1.z, gB1.z, gB1.w)));
        jA += 2; jB += 2;
    }
    // drain A (2-way then 1)
    for (; jA + 2 <= jA1; jA += 2) {
        float4 e0 = edataA[jA], e1 = edataA[jA+1];
        float4 g0 = G2[(size_t)__float_as_int(e0.w)*32 + o];
        float4 g1 = G2[(size_t)__float_as_int(e1.w)*32 + o];
        aA0 += fmaf(e0.x, g0.x, fmaf(e0.y, g0.y, fmaf(e0.z, g0.z, g0.w)));
        aA1 += fmaf(e1.x, g1.x, fmaf(e1.y, g1.y, fmaf(e1.z, g1.z, g1.w)));
    }
    if (jA < jA1) {
        float4 e0 = edataA[jA];
        float4 g0 = G2[(size_t)__float_as_int(e0.w)*32 + o];
        aA0 += fmaf(e0.x, g0.x, fmaf(e0.y, g0.y, fmaf(e0.z, g0.z, g0.w)));
    }
    // drain B
    for (; jB + 2 <= jB1; jB += 2) {
        float4 e0 = edataA[jB], e1 = edataA[jB+1];
        float4 g0 = G2[(size_t)__float_as_int(e0.w)*32 + o];
        float4 g1 = G2[(size_t)__float_as_int(e1.w)*32 + o];
        aB0 += fmaf(e0.x, g0.x, fmaf(e0.y, g0.y, fmaf(e0.z, g0.z, g0.w)));
        aB1 += fmaf(e1.x, g1.x, fmaf(e1.y, g1.y, fmaf(e1.z, g1.z, g1.w)));
    }
    if (jB < jB1) {
        float4 e0 = edataA[jB];
        float4 g0 = G2[(size_t)__float_as_int(e0.w)*32 + o];
        aB0 += fmaf(e0.x, g0.x, fmaf(e0.y, g0.y, fmaf(e0.z, g0.z, g0.w)));
    }

    conv2_epilogue(nA, o, aA0 + aA1, h1, root2, b2, Wf1, bf1, Wf2, bf2, out);
    conv2_epilogue(nB, o, aB0 + aB1, h1, root2, b2, Wf1, bf1, Wf2, bf2, out);
}

extern "C" void kernel_launch(void* const* d_in, const int* in_sizes, int n_in,
                              void* d_out, int out_size, void* d_ws, size_t ws_size,
                              hipStream_t stream) {
    const float* x     = (const float*)d_in[0];
    const int*   ei    = (const int*)  d_in[1];
    const float* ea    = (const float*)d_in[2];
    const float* Wn1   = (const float*)d_in[3];
    const float* bn1   = (const float*)d_in[4];
    const float* root1 = (const float*)d_in[5];
    const float* b1    = (const float*)d_in[6];
    const float* Wn2   = (const float*)d_in[7];
    const float* bn2   = (const float*)d_in[8];
    const float* root2 = (const float*)d_in[9];
    const float* b2    = (const float*)d_in[10];
    const float* Wf1   = (const float*)d_in[11];
    const float* bf1   = (const float*)d_in[12];
    const float* Wf2   = (const float*)d_in[13];
    const float* bf2   = (const float*)d_in[14];
    float* out = (float*)d_out;

    // workspace carve (~78 MB)
    float*  h1     = (float*)d_ws;                        // [N,32]
    float4* G2     = (float4*)(h1 + (size_t)N_NODES*32);  // [N,32] float4
    float4* edataA = G2 + (size_t)N_NODES*32;             // [E]
    float4* edataB = edataA + N_EDGES;                    // [E]
    int*    deg    = (int*)(edataB + N_EDGES);            // [N]
    int*    rowptr = deg + N_NODES;                       // [N+1]
    int*    cursor = rowptr + N_NODES + 1;                // [N]
    int*    psum   = cursor + N_NODES;                    // [SCAN_BLOCKS]

    hipMemsetAsync(deg, 0, N_NODES * sizeof(int), stream);

    int eb   = (N_EDGES + 255) / 256;                     // 1563
    int nb32 = (N_NODES * 32 + 255) / 256;                // 12500
    int hb32 = (N_HALF  * 32 + 255) / 256;                // 6250

    hist_kernel   <<<eb, 256, 0, stream>>>(ei, deg);
    scanA_kernel  <<<SCAN_BLOCKS, 256, 0, stream>>>(deg, rowptr, psum);
    scanBC_kernel <<<SCAN_BLOCKS, 256, 0, stream>>>(psum, rowptr, cursor);
    scatter_kernel<<<eb, 256, 0, stream>>>(ei, ea, x, cursor, edataA, edataB);
    conv1_kernel  <<<nb32, 256, 0, stream>>>(rowptr, edataA, edataB, x, Wn1, bn1, root1, b1, h1);
    prep2_kernel  <<<1536, 256, 0, stream>>>(h1, Wn2, bn2, G2);
    conv2_kernel  <<<hb32, 256, 0, stream>>>(rowptr, edataA, G2, h1, root2, b2,
                                             Wf1, bf1, Wf2, bf2, out);
}

// Round 7
// 156.975 us; speedup vs baseline: 1.2118x; 1.1220x over previous
//
#include <hip/hip_runtime.h>

#define N_NODES 100000
#define N_EDGES 400000
#define SCAN_BLOCKS ((N_NODES + 255) / 256)   // 391

// ---------- build CSR by dst: histogram ----------
__global__ __launch_bounds__(256) void hist_kernel(const int* __restrict__ ei,
                                                   int* __restrict__ deg) {
    int e = blockIdx.x * 256 + threadIdx.x;
    if (e < N_EDGES) atomicAdd(&deg[ei[N_EDGES + e]], 1);
}

// block-local exclusive scan of deg -> rowptr(local), block sums -> psum
__global__ __launch_bounds__(256) void scanA_kernel(const int* __restrict__ deg,
                                                    int* __restrict__ rowptr,
                                                    int* __restrict__ psum) {
    __shared__ int sm[256];
    int i = blockIdx.x * 256 + threadIdx.x;
    int v = (i < N_NODES) ? deg[i] : 0;
    sm[threadIdx.x] = v;
    __syncthreads();
    #pragma unroll
    for (int off = 1; off < 256; off <<= 1) {
        int t = (threadIdx.x >= off) ? sm[threadIdx.x - off] : 0;
        __syncthreads();
        sm[threadIdx.x] += t;
        __syncthreads();
    }
    if (i < N_NODES) rowptr[i] = sm[threadIdx.x] - v;
    if (threadIdx.x == 255) psum[blockIdx.x] = sm[255];
}

// merged scanB+scanC
__global__ __launch_bounds__(256) void scanBC_kernel(const int* __restrict__ psum,
                                                     int* __restrict__ rowptr,
                                                     int* __restrict__ cursor) {
    __shared__ int sm[8];
    int bid = blockIdx.x, tid = threadIdx.x;
    int acc = 0;
    for (int t = tid; t < bid; t += 256) acc += psum[t];
    #pragma unroll
    for (int off = 32; off; off >>= 1) acc += __shfl_down(acc, off, 64);
    if ((tid & 63) == 0) sm[tid >> 6] = acc;
    __syncthreads();
    int base = sm[0] + sm[1] + sm[2] + sm[3];
    int i = bid * 256 + tid;
    if (i < N_NODES) {
        int r = rowptr[i] + base;
        rowptr[i] = r;
        cursor[i] = r;
    }
    if (i == 0) rowptr[N_NODES] = N_EDGES;
}

// scatter edge payload into dst-sorted slots: A={ea0,ea1,ea2,src}, B={x[s],0}
__global__ __launch_bounds__(256) void scatter_kernel(const int* __restrict__ ei,
                                                      const float* __restrict__ ea,
                                                      const float* __restrict__ x,
                                                      int* __restrict__ cursor,
                                                      float4* __restrict__ edataA,
                                                      float4* __restrict__ edataB) {
    int e = blockIdx.x * 256 + threadIdx.x;
    if (e >= N_EDGES) return;
    int s = ei[e], d = ei[N_EDGES + e];
    int pos = atomicAdd(&cursor[d], 1);
    edataA[pos] = make_float4(ea[e*3], ea[e*3+1], ea[e*3+2], __int_as_float(s));
    edataB[pos] = make_float4(x[s*3], x[s*3+1], x[s*3+2], 0.f);
}

// ---------- conv1 aggregation + node update (R4 version) ----------
__global__ __launch_bounds__(256) void conv1_kernel(const int* __restrict__ rowptr,
                                                    const float4* __restrict__ edataA,
                                                    const float4* __restrict__ edataB,
                                                    const float* __restrict__ x,
                                                    const float* __restrict__ Wn1,
                                                    const float* __restrict__ bn1,
                                                    const float* __restrict__ root1,
                                                    const float* __restrict__ b1,
                                                    float* __restrict__ h1) {
    int gid = blockIdx.x * 256 + threadIdx.x;
    int n = gid >> 5, o = gid & 31;
    if (n >= N_NODES) return;
    float W[3][3], bb[3];
    #pragma unroll
    for (int d2 = 0; d2 < 3; ++d2)
        #pragma unroll
        for (int d = 0; d < 3; ++d) W[d2][d] = Wn1[d2*96 + d*32 + o];
    #pragma unroll
    for (int d = 0; d < 3; ++d) bb[d] = bn1[d*32 + o];

    int j0 = rowptr[n], j1 = rowptr[n + 1];
    float acc0 = 0.f, acc1 = 0.f;
    int j = j0;
    for (; j + 2 <= j1; j += 2) {
        float4 eA0 = edataA[j],   eB0 = edataB[j];
        float4 eA1 = edataA[j+1], eB1 = edataB[j+1];
        float wd0 = fmaf(eA0.x, W[0][0], fmaf(eA0.y, W[1][0], fmaf(eA0.z, W[2][0], bb[0])));
        float wd1 = fmaf(eA0.x, W[0][1], fmaf(eA0.y, W[1][1], fmaf(eA0.z, W[2][1], bb[1])));
        float wd2 = fmaf(eA0.x, W[0][2], fmaf(eA0.y, W[1][2], fmaf(eA0.z, W[2][2], bb[2])));
        acc0 += fmaf(eB0.x, wd0, fmaf(eB0.y, wd1, eB0.z * wd2));
        float ud0 = fmaf(eA1.x, W[0][0], fmaf(eA1.y, W[1][0], fmaf(eA1.z, W[2][0], bb[0])));
        float ud1 = fmaf(eA1.x, W[0][1], fmaf(eA1.y, W[1][1], fmaf(eA1.z, W[2][1], bb[1])));
        float ud2 = fmaf(eA1.x, W[0][2], fmaf(eA1.y, W[1][2], fmaf(eA1.z, W[2][2], bb[2])));
        acc1 += fmaf(eB1.x, ud0, fmaf(eB1.y, ud1, eB1.z * ud2));
    }
    if (j < j1) {
        float4 eA0 = edataA[j], eB0 = edataB[j];
        float wd0 = fmaf(eA0.x, W[0][0], fmaf(eA0.y, W[1][0], fmaf(eA0.z, W[2][0], bb[0])));
        float wd1 = fmaf(eA0.x, W[0][1], fmaf(eA0.y, W[1][1], fmaf(eA0.z, W[2][1], bb[1])));
        float wd2 = fmaf(eA0.x, W[0][2], fmaf(eA0.y, W[1][2], fmaf(eA0.z, W[2][2], bb[2])));
        acc0 += fmaf(eB0.x, wd0, fmaf(eB0.y, wd1, eB0.z * wd2));
    }
    float v = acc0 + acc1 + b1[o];
    v = fmaf(x[n*3],   root1[o],      v);
    v = fmaf(x[n*3+1], root1[32 + o], v);
    v = fmaf(x[n*3+2], root1[64 + o], v);
    h1[(size_t)n*32 + o] = fmaxf(v, 0.f);
}

// ---------- per-node precompute G2[n] = [hW0 | hW1 | hW2 | hB] ----------
__global__ __launch_bounds__(256) void prep2_kernel(const float* __restrict__ h1,
                                                    const float* __restrict__ Wn2,
                                                    const float* __restrict__ bn2,
                                                    float4* __restrict__ G2) {
    int o = threadIdx.x & 31;
    float w0[32], w1[32], w2[32], w3[32];
    #pragma unroll
    for (int i = 0; i < 32; ++i) {
        w0[i] = Wn2[         i*32 + o];
        w1[i] = Wn2[1024 +   i*32 + o];
        w2[i] = Wn2[2048 +   i*32 + o];
        w3[i] = bn2[         i*32 + o];
    }
    int g = (blockIdx.x * 256 + threadIdx.x) >> 5;
    int gstep = (gridDim.x * 256) >> 5;
    for (int n = g; n < N_NODES; n += gstep) {
        const float* __restrict__ hr = h1 + (size_t)n * 32;
        float g0 = 0.f, g1 = 0.f, g2 = 0.f, g3 = 0.f;
        #pragma unroll
        for (int i = 0; i < 32; ++i) {
            float hi = hr[i];
            g0 = fmaf(hi, w0[i], g0);
            g1 = fmaf(hi, w1[i], g1);
            g2 = fmaf(hi, w2[i], g2);
            g3 = fmaf(hi, w3[i], g3);
        }
        G2[(size_t)n*32 + o] = make_float4(g0, g1, g2, g3);
    }
}

// ---------- conv2: PURE gather (no epilogue) ----------
__global__ __launch_bounds__(256) void conv2_kernel(const int* __restrict__ rowptr,
                                                    const float4* __restrict__ edataA,
                                                    const float4* __restrict__ G2,
                                                    float* __restrict__ h2pre) {
    int gid = blockIdx.x * 256 + threadIdx.x;
    int n = gid >> 5, o = gid & 31;
    if (n >= N_NODES) return;
    int j0 = rowptr[n], j1 = rowptr[n + 1];
    float a0 = 0.f, a1 = 0.f;
    int j = j0;
    for (; j + 2 <= j1; j += 2) {
        float4 e0 = edataA[j], e1 = edataA[j+1];
        float4 g0 = G2[(size_t)__float_as_int(e0.w)*32 + o];
        float4 g1 = G2[(size_t)__float_as_int(e1.w)*32 + o];
        a0 += fmaf(e0.x, g0.x, fmaf(e0.y, g0.y, fmaf(e0.z, g0.z, g0.w)));
        a1 += fmaf(e1.x, g1.x, fmaf(e1.y, g1.y, fmaf(e1.z, g1.z, g1.w)));
    }
    if (j < j1) {
        float4 e0 = edataA[j];
        float4 g0 = G2[(size_t)__float_as_int(e0.w)*32 + o];
        a0 += fmaf(e0.x, g0.x, fmaf(e0.y, g0.y, fmaf(e0.z, g0.z, g0.w)));
    }
    h2pre[(size_t)n*32 + o] = a0 + a1;
}

// ---------- node2: root2 + ReLU + FC1 + FC2, node-per-thread (uniform weights) ----------
__global__ __launch_bounds__(256) void node2_kernel(const float* __restrict__ h2pre,
                                                    const float* __restrict__ h1,
                                                    const float* __restrict__ root2,
                                                    const float* __restrict__ b2,
                                                    const float* __restrict__ Wf1,
                                                    const float* __restrict__ bf1,
                                                    const float* __restrict__ Wf2,
                                                    const float* __restrict__ bf2,
                                                    float* __restrict__ out) {
    int n = blockIdx.x * 256 + threadIdx.x;
    if (n >= N_NODES) return;
    float hr[32];
    const float4* hv = (const float4*)(h1 + (size_t)n * 32);
    #pragma unroll
    for (int j4 = 0; j4 < 8; ++j4) {
        float4 t = hv[j4];
        hr[j4*4+0] = t.x; hr[j4*4+1] = t.y; hr[j4*4+2] = t.z; hr[j4*4+3] = t.w;
    }
    const float4* av = (const float4*)(h2pre + (size_t)n * 32);
    float h2[32];
    #pragma unroll
    for (int j4 = 0; j4 < 8; ++j4) {
        float4 a = av[j4];
        #pragma unroll
        for (int k = 0; k < 4; ++k) {
            int j = j4*4 + k;                       // wave-uniform -> s_load weights
            float acc = (&a.x)[k] + b2[j];
            #pragma unroll
            for (int i = 0; i < 32; ++i)
                acc = fmaf(hr[i], root2[i*32 + j], acc);
            h2[j] = fmaxf(acc, 0.f);
        }
    }
    float acc2 = bf2[0];
    #pragma unroll
    for (int j = 0; j < 32; ++j) {
        float a = bf1[j];
        #pragma unroll
        for (int i = 0; i < 32; ++i) a = fmaf(h2[i], Wf1[i*32 + j], a);
        acc2 = fmaf(fmaxf(a, 0.f), Wf2[j], acc2);
    }
    out[n] = acc2;
}

extern "C" void kernel_launch(void* const* d_in, const int* in_sizes, int n_in,
                              void* d_out, int out_size, void* d_ws, size_t ws_size,
                              hipStream_t stream) {
    const float* x     = (const float*)d_in[0];
    const int*   ei    = (const int*)  d_in[1];
    const float* ea    = (const float*)d_in[2];
    const float* Wn1   = (const float*)d_in[3];
    const float* bn1   = (const float*)d_in[4];
    const float* root1 = (const float*)d_in[5];
    const float* b1    = (const float*)d_in[6];
    const float* Wn2   = (const float*)d_in[7];
    const float* bn2   = (const float*)d_in[8];
    const float* root2 = (const float*)d_in[9];
    const float* b2    = (const float*)d_in[10];
    const float* Wf1   = (const float*)d_in[11];
    const float* bf1   = (const float*)d_in[12];
    const float* Wf2   = (const float*)d_in[13];
    const float* bf2   = (const float*)d_in[14];
    float* out = (float*)d_out;

    // workspace carve (~82 MB)
    float*  h1     = (float*)d_ws;                        // [N,32]
    float*  h2pre  = h1 + (size_t)N_NODES*32;             // [N,32]
    float4* G2     = (float4*)(h2pre + (size_t)N_NODES*32); // [N,32] float4
    float4* edataA = G2 + (size_t)N_NODES*32;             // [E]
    float4* edataB = edataA + N_EDGES;                    // [E]
    int*    deg    = (int*)(edataB + N_EDGES);            // [N]
    int*    rowptr = deg + N_NODES;                       // [N+1]
    int*    cursor = rowptr + N_NODES + 1;                // [N]
    int*    psum   = cursor + N_NODES;                    // [SCAN_BLOCKS]

    hipMemsetAsync(deg, 0, N_NODES * sizeof(int), stream);

    int eb   = (N_EDGES + 255) / 256;                     // 1563
    int nb   = (N_NODES + 255) / 256;                     // 391
    int nb32 = (N_NODES * 32 + 255) / 256;                // 12500

    hist_kernel   <<<eb, 256, 0, stream>>>(ei, deg);
    scanA_kernel  <<<SCAN_BLOCKS, 256, 0, stream>>>(deg, rowptr, psum);
    scanBC_kernel <<<SCAN_BLOCKS, 256, 0, stream>>>(psum, rowptr, cursor);
    scatter_kernel<<<eb, 256, 0, stream>>>(ei, ea, x, cursor, edataA, edataB);
    conv1_kernel  <<<nb32, 256, 0, stream>>>(rowptr, edataA, edataB, x, Wn1, bn1, root1, b1, h1);
    prep2_kernel  <<<1536, 256, 0, stream>>>(h1, Wn2, bn2, G2);
    conv2_kernel  <<<nb32, 256, 0, stream>>>(rowptr, edataA, G2, h2pre);
    node2_kernel  <<<nb, 256, 0, stream>>>(h2pre, h1, root2, b2, Wf1, bf1, Wf2, bf2, out);
}